// Round 5
// baseline (1672.494 us; speedup 1.0000x reference)
//
#include <hip/hip_runtime.h>

#define NN     100000
#define NB     1563          // ceil(100000 / 64)
#define LN_EPS 1e-5f
#define SLOPE  0.01f

typedef __bf16 bf16x8 __attribute__((ext_vector_type(8)));
typedef float  f32x16 __attribute__((ext_vector_type(16)));
typedef unsigned short u16;
typedef unsigned int   u32;

union Pack8 { uint4 u4; bf16x8 bf; u16 s[8]; };

__device__ __forceinline__ u16 f2bf(float x){
    u32 b = __float_as_uint(x);
    b += 0x7fffu + ((b >> 16) & 1u);
    return (u16)(b >> 16);
}

// Pack w[1024][1024] fp32 (row = output col i, inner = k) into bf16 B-fragment
// order for mfma_32x32x16: Wp uint4 idx = (k>>3)*1024 + col, holding
// W[col][k..k+7]. B-frag load for (col, ks, hi) is uint4 (ks*2+hi)*1024+col.
__global__ __launch_bounds__(1024) void prep_weights(
    const float* __restrict__ wa, const float* __restrict__ wb,
    const float* __restrict__ wc, const float* __restrict__ wd,
    u16* __restrict__ dst)
{
    int m = blockIdx.y;
    const float* src = (m==0)? wa : (m==1)? wb : (m==2)? wc : wd;
    u16* d = dst + (size_t)m * (1024u*1024u);
    int tid = blockIdx.x * blockDim.x + threadIdx.x;   // 0..131071
    int sub = tid & 3;
    int row = (tid >> 2) & 1023;
    int kb  = tid >> 12;                               // 0..31
    const float4* s4 = (const float4*)(src + row*1024 + kb*32 + sub*8);
    float4 a = s4[0], b = s4[1];
    Pack8 p;
    p.s[0]=f2bf(a.x); p.s[1]=f2bf(a.y); p.s[2]=f2bf(a.z); p.s[3]=f2bf(a.w);
    p.s[4]=f2bf(b.x); p.s[5]=f2bf(b.y); p.s[6]=f2bf(b.z); p.s[7]=f2bf(b.w);
    ((uint4*)d)[(kb*4 + sub)*1024 + row] = p.u4;       // (k0>>3)*1024 + row
}

// 32x32x16 GEMM: one wave computes cols C0..C0+63 x all 64 nodes.
// acc = 2x2 f32x16 = 64 AGPR (same budget as the old 16x16 shape) but HALF
// the MFMA instr count and +15% MFMA rate (m06/m119: 2382-2495 vs 2075 TF).
// Per-iter load regs: 4 uint4 (was 8) -> lighter, no spill risk at unroll 2.
// C layout (m74/m101): row=(reg&3)+8*(reg>>2)+4*(lane>>5), col=lane&31.
__device__ __forceinline__ void gemm_quad32(
    const u16* __restrict__ Wp, const u16* xs,
    int C0, int lane31, int hi, f32x16 acc[2][2])
{
    const uint4* bb = (const uint4*)Wp + hi*1024 + C0 + lane31;
    const uint4* ab = (const uint4*)xs + hi*64  + lane31;
    #pragma unroll
    for (int t=0; t<2; ++t)
      #pragma unroll
      for (int rt=0; rt<2; ++rt)
        #pragma unroll
        for (int e=0; e<16; ++e) acc[t][rt][e] = 0.f;
    #pragma unroll 2
    for (int ks=0; ks<64; ++ks){
        Pack8 b0, b1, a0, a1;
        b0.u4 = bb[ks*2048];
        b1.u4 = bb[ks*2048 + 32];
        a0.u4 = ab[ks*128];
        a1.u4 = ab[ks*128 + 32];
        acc[0][0] = __builtin_amdgcn_mfma_f32_32x32x16_bf16(a0.bf, b0.bf, acc[0][0], 0,0,0);
        acc[0][1] = __builtin_amdgcn_mfma_f32_32x32x16_bf16(a1.bf, b0.bf, acc[0][1], 0,0,0);
        acc[1][0] = __builtin_amdgcn_mfma_f32_32x32x16_bf16(a0.bf, b1.bf, acc[1][0], 0,0,0);
        acc[1][1] = __builtin_amdgcn_mfma_f32_32x32x16_bf16(a1.bf, b1.bf, acc[1][1], 0,0,0);
    }
}

// LDS layout (floats):
//   [0, 32832)       : xs (bf16 activations, 131072 B) / later sbuf (fp32 h2)
//   [32832, +64*VSTR): vbuf, per-node padded v rows
//   then 128 floats  : stats (64 nodes x {sum, sumsq})
template<int MDIM>
__device__ __forceinline__ void gal_body(
    const int blk, char* smem,
    const float* __restrict__ f,
    const float* __restrict__ ln1g, const float* __restrict__ ln1b,
    const float* __restrict__ ln2g, const float* __restrict__ ln2b,
    const float* __restrict__ b2,
    const u16* __restrict__ Wp1, const u16* __restrict__ Wp2,
    float* __restrict__ outp)
{
    constexpr int VSTR = 32*MDIM + 4;           // padded node stride (floats)
    constexpr int SBS  = 64*32 + 4;             // sbuf per-slot stride = 2052
    u16*   xs    = (u16*)smem;
    float* sbuf  = (float*)smem;
    float* vbuf  = (float*)smem + 32832;
    float* stats = (float*)smem + 32832 + 64*VSTR;

    const int tid    = threadIdx.x;            // 0..1023
    const int lane   = tid & 63;
    const int wv     = tid >> 6;               // wave 0..15
    const int lane31 = lane & 31;
    const int hi     = lane >> 5;              // k-half / C-row offset 4*hi
    const int node0  = blk * 64;

    // ---- Phase 0: zero stats, stage v tile (float4, padded, zero-fill)
    if (tid < 128) stats[tid] = 0.f;
    {
        float4* vbuf4 = (float4*)vbuf;
        const int gv4  = node0*8*MDIM;          // block base in float4 units
        const int lim4 = NN*8*MDIM;
        for (int i = tid; i < 64*8*MDIM; i += 1024){
            int nd = i / (8*MDIM);
            int r4 = i - nd*(8*MDIM);
            float4 val = (gv4 + i < lim4) ? ((const float4*)f)[gv4 + i]
                                          : (float4){0.f,0.f,0.f,0.f};
            vbuf4[nd*(VSTR/4) + r4] = val;
        }
    }
    __syncthreads();

    // ---- Phase 1: gram + LN1 + lrelu -> xs (bf16, [k>>3][node][k&7])
    // 16 threads/node; thread j owns k = j*64..j*64+63. Dots recomputed in
    // the pack pass (r1/r2/r4 lesson: ANY form holding >~32 extra live floats
    // spills past the 64-arch-VGPR pool -> scratch traffic; and P1 LDS issue
    // is NOT critical path (r4: -250 LDS instr/thread = flat). Keep scalar.
    {
        const int n = tid >> 4;          // node
        const int j = tid & 15;
        const float* vn = vbuf + n*VSTR;
        float va[2][MDIM];
        #pragma unroll
        for (int c=0;c<MDIM;++c){ va[0][c]=vn[(j*2)*MDIM+c]; va[1][c]=vn[(j*2+1)*MDIM+c]; }
        float sum=0.f, ssum=0.f;
        #pragma unroll
        for (int b=0;b<32;++b){
            float d0=0.f, d1=0.f;
            #pragma unroll
            for (int c=0;c<MDIM;++c){ float vb = vn[b*MDIM+c]; d0 += va[0][c]*vb; d1 += va[1][c]*vb; }
            sum += d0+d1; ssum += d0*d0 + d1*d1;
        }
        #pragma unroll
        for (int st=1; st<16; st<<=1){ sum += __shfl_xor(sum, st); ssum += __shfl_xor(ssum, st); }
        float mu   = sum * (1.f/1024.f);
        float rstd = rsqrtf(ssum*(1.f/1024.f) - mu*mu + LN_EPS);
        #pragma unroll
        for (int jb=0;jb<8;++jb){
            Pack8 p;
            const int ai = jb >> 2;
            #pragma unroll
            for (int l=0;l<8;++l){
                int b = (jb*8+l) & 31;
                float d = 0.f;
                #pragma unroll
                for (int c=0;c<MDIM;++c) d += va[ai][c]*vn[b*MDIM+c];
                int k = j*64 + jb*8 + l;
                float x = (d - mu)*rstd*ln1g[k] + ln1b[k];
                x = (x >= 0.f)? x : SLOPE*x;
                p.s[l] = f2bf(x);
            }
            ((uint4*)xs)[(j*8+jb)*64 + n] = p.u4;
        }
    }
    __syncthreads();

    // ---- Phase 2: h1 = x1 @ W1^T, one pass, wave wv owns cols wv*64..+63.
    // Stats: 32-value/32-lane fold, TWO sequential passes (sum then sumsq)
    // to keep live floats <=32+working under the 64-VGPR wall.
    {
        f32x16 acc[2][2];
        gemm_quad32(Wp1, xs, wv*64, lane31, hi, acc);
        const int nd_f = (lane31>>4)*32 + (lane31&3) + 8*((lane31>>2)&3) + 4*hi;
        {
            float p_[32];
            #pragma unroll
            for (int idx=0; idx<32; ++idx){
                int rt = idx>>4, rg = idx&15;
                p_[idx] = acc[0][rt][rg] + acc[1][rt][rg];
            }
            #pragma unroll
            for (int m=16; m>=1; m>>=1){
                const bool up = (lane31 & m) != 0;
                #pragma unroll
                for (int i=0; i<m; ++i){
                    float sp = up ? p_[i]   : p_[i+m];
                    float kp = up ? p_[i+m] : p_[i];
                    p_[i] = kp + __shfl_xor(sp, m);
                }
            }
            atomicAdd(&stats[2*nd_f], p_[0]);
        }
        {
            float p_[32];
            #pragma unroll
            for (int idx=0; idx<32; ++idx){
                int rt = idx>>4, rg = idx&15;
                float h0 = acc[0][rt][rg], h1 = acc[1][rt][rg];
                p_[idx] = h0*h0 + h1*h1;
            }
            #pragma unroll
            for (int m=16; m>=1; m>>=1){
                const bool up = (lane31 & m) != 0;
                #pragma unroll
                for (int i=0; i<m; ++i){
                    float sp = up ? p_[i]   : p_[i+m];
                    float kp = up ? p_[i+m] : p_[i];
                    p_[i] = kp + __shfl_xor(sp, m);
                }
            }
            atomicAdd(&stats[2*nd_f+1], p_[0]);
        }
        __syncthreads();   // stats final AND all GEMM1 xs reads drained

        // ---- Phase 3: LN2 + lrelu applied to acc in regs -> x2 into xs
        float g2c[2], b2c[2];
        #pragma unroll
        for (int t=0; t<2; ++t){
            int col = wv*64 + t*32 + lane31;
            g2c[t] = ln2g[col];
            b2c[t] = ln2b[col];
        }
        #pragma unroll
        for (int rt=0; rt<2; ++rt)
          #pragma unroll
          for (int rg=0; rg<16; ++rg){
            int nd = rt*32 + (rg&3) + 8*((rg>>2)&3) + 4*hi;
            float mu   = stats[2*nd]*(1.f/1024.f);
            float rstd = rsqrtf(stats[2*nd+1]*(1.f/1024.f) - mu*mu + LN_EPS);
            #pragma unroll
            for (int t=0; t<2; ++t){
                float h = acc[t][rt][rg];
                float x = (h - mu)*rstd*g2c[t] + b2c[t];
                x = (x >= 0.f)? x : SLOPE*x;
                int col = wv*64 + t*32 + lane31;
                xs[(col>>3)*512 + nd*8 + (col&7)] = f2bf(x);
            }
          }
    }
    __syncthreads();

    // ---- Phase 4: h2 = x2 @ W2^T + b2 (acc 2x2 f32x16 live). Wave wv owns
    // a = 2wv, 2wv+1 (a = col/32 = 2wv+t), so round r = wv>>3 stages the
    // CONTIGUOUS a-range [16r, 16r+16): slot = (wv&7)*2+t, b = lane31.
    // Consume threads keep both rounds in registers, park in a contiguous
    // LDS image, one float4 pass writes full 128B lines exactly once.
    {
        f32x16 acc[2][2];
        gemm_quad32(Wp2, xs, wv*64, lane31, hi, acc);
        float bias[2];
        #pragma unroll
        for (int t=0; t<2; ++t)
            bias[t] = b2[wv*64 + t*32 + lane31];
        __syncthreads();   // all xs reads complete before sbuf overwrite

        const int nd_c = tid >> 4;      // consume node
        const int s_c  = tid & 15;      // consume strip -> a = r*16 + s_c
        const int myr  = wv >> 3;
        float keep[2][MDIM];

        #pragma unroll
        for (int r=0; r<2; ++r){
            if (myr == r){
                #pragma unroll
                for (int t=0; t<2; ++t){
                    const int slot = (wv&7)*2 + t;
                    #pragma unroll
                    for (int rt=0; rt<2; ++rt)
                      #pragma unroll
                      for (int rg=0; rg<16; ++rg){
                        int nd = rt*32 + (rg&3) + 8*((rg>>2)&3) + 4*hi;
                        sbuf[slot*SBS + nd*32 + lane31] = acc[t][rt][rg] + bias[t];
                      }
                }
            }
            __syncthreads();
            // consume: thread -> (node = tid>>4, strip s_c, a = r*16 + s_c)
            {
                const float* hp = sbuf + s_c*SBS + nd_c*32;
                float e[32];
                #pragma unroll
                for (int rr=0;rr<8;++rr){
                    float4 v4 = ((const float4*)hp)[rr];
                    e[4*rr]=v4.x; e[4*rr+1]=v4.y; e[4*rr+2]=v4.z; e[4*rr+3]=v4.w;
                }
                float mx = e[0];
                #pragma unroll
                for (int b=1;b<32;++b) mx = fmaxf(mx, e[b]);
                float sm = 0.f;
                #pragma unroll
                for (int b=0;b<32;++b){ e[b] = __expf(e[b]-mx); sm += e[b]; }
                float inv = 1.f / sm;
                float oacc[MDIM];
                #pragma unroll
                for (int c=0;c<MDIM;++c) oacc[c]=0.f;
                const float4* vr = (const float4*)(vbuf + nd_c*VSTR);
                #pragma unroll
                for (int rr=0; rr<8*MDIM; ++rr){
                    float4 v4 = vr[rr];
                    #pragma unroll
                    for (int t=0;t<4;++t){
                        const int fi = 4*rr+t;
                        const int b  = fi/MDIM;
                        const int c  = fi - b*MDIM;
                        float comp = (t==0)?v4.x:(t==1)?v4.y:(t==2)?v4.z:v4.w;
                        oacc[c] += e[b]*comp;
                    }
                }
                #pragma unroll
                for (int c=0;c<MDIM;++c) keep[r][c] = oacc[c]*inv;
            }
            __syncthreads();   // strip reads done (r0: before restage; r1: before img)
        }

        // park both rounds into contiguous image at smem base (strips dead)
        {
            float* img = sbuf;
            #pragma unroll
            for (int c=0;c<MDIM;++c){
                img[nd_c*(32*MDIM) + (     s_c)*MDIM + c] = keep[0][c];
                img[nd_c*(32*MDIM) + (16 + s_c)*MDIM + c] = keep[1][c];
            }
        }
        __syncthreads();

        // coalesced full-line writeback, float4, each line written once
        {
            const float4* img4 = (const float4*)sbuf;
            float4* out4 = (float4*)(outp + (size_t)node0*(32*MDIM));
            constexpr int NPV = 8*MDIM;          // float4 per node
            for (int i = tid; i < 64*NPV; i += 1024){
                int nd = (MDIM==1) ? (i >> 3) : (i / NPV);
                if (node0 + nd < NN) out4[i] = img4[i];
            }
        }
    }
}

// Single launch, CONTIGUOUS type halves. Blocks dispatch ~in gid order with
// a ~256-block resident window (1 block/CU), so contiguous halves keep one
// 4MB weight set per XCD except during the brief boundary crossing, while
// the scheduler back-fills the first half's drain with second-half blocks.
// Long type (MDIM3) first, short last -> minimal final drain.
__global__ __launch_bounds__(1024, 4) void gal_fused_all(
    const float* __restrict__ f0, const float* __restrict__ f1,
    const float* __restrict__ ln1g0, const float* __restrict__ ln1b0,
    const float* __restrict__ ln2g0, const float* __restrict__ ln2b0,
    const float* __restrict__ b2_0,
    const float* __restrict__ ln1g1, const float* __restrict__ ln1b1,
    const float* __restrict__ ln2g1, const float* __restrict__ ln2b1,
    const float* __restrict__ b2_1,
    const u16* __restrict__ wp, float* __restrict__ out)
{
    extern __shared__ char smem[];
    const int gid = blockIdx.x;
    if (gid < NB)
        gal_body<3>(gid, smem, f1, ln1g1, ln1b1, ln2g1, ln2b1, b2_1,
                    wp + 2097152,  wp + 3145728, out + (size_t)NN*32);
    else
        gal_body<1>(gid - NB, smem, f0, ln1g0, ln1b0, ln2g0, ln2b0, b2_0,
                    wp,            wp + 1048576, out);
}

extern "C" void kernel_launch(void* const* d_in, const int* in_sizes, int n_in,
                              void* d_out, int out_size, void* d_ws, size_t ws_size,
                              hipStream_t stream)
{
    const float* f0    = (const float*)d_in[0];
    const float* f1    = (const float*)d_in[1];
    const float* ln1g0 = (const float*)d_in[2];
    const float* ln1b0 = (const float*)d_in[3];
    const float* w1_0  = (const float*)d_in[4];
    const float* ln2g0 = (const float*)d_in[5];
    const float* ln2b0 = (const float*)d_in[6];
    const float* w2_0  = (const float*)d_in[7];
    const float* b2_0  = (const float*)d_in[8];
    const float* ln1g1 = (const float*)d_in[9];
    const float* ln1b1 = (const float*)d_in[10];
    const float* w1_1  = (const float*)d_in[11];
    const float* ln2g1 = (const float*)d_in[12];
    const float* ln2b1 = (const float*)d_in[13];
    const float* w2_1  = (const float*)d_in[14];
    const float* b2_1  = (const float*)d_in[15];
    float* out = (float*)d_out;
    u16* wp = (u16*)d_ws;    // 4 packed matrices x 2 MB = 8 MB scratch

    const int smem = (32832 + 64*(32*3+4) + 128)*4;   // 157440 (max of both)
    (void)hipFuncSetAttribute(reinterpret_cast<const void*>(&gal_fused_all),
                              hipFuncAttributeMaxDynamicSharedMemorySize, smem);

    prep_weights<<<dim3(128,4), 1024, 0, stream>>>(w1_0, w2_0, w1_1, w2_1, wp);
    gal_fused_all<<<2*NB, 1024, smem, stream>>>(f0, f1,
        ln1g0, ln1b0, ln2g0, ln2b0, b2_0,
        ln1g1, ln1b1, ln2g1, ln2b1, b2_1,
        wp, out);
}

// Round 6
// 1252.406 us; speedup vs baseline: 1.3354x; 1.3354x over previous
//
#include <hip/hip_runtime.h>

#define NN     100000
#define NB     1563          // ceil(100000 / 64)
#define LN_EPS 1e-5f
#define SLOPE  0.01f

typedef __bf16 bf16x8 __attribute__((ext_vector_type(8)));
typedef float  f32x4  __attribute__((ext_vector_type(4)));
typedef unsigned short u16;
typedef unsigned int   u32;

union Pack8 { uint4 u4; bf16x8 bf; u16 s[8]; };

__device__ __forceinline__ u16 f2bf(float x){
    u32 b = __float_as_uint(x);
    b += 0x7fffu + ((b >> 16) & 1u);
    return (u16)(b >> 16);
}

// Pack w[1024][1024] fp32 (row = output col i, inner = k) into bf16 B-fragment
// order: Wp[k>>5][i][k&31]; B-frag load for (col,ks) is uint4 (ks*1024+col)*4+q.
__global__ __launch_bounds__(1024) void prep_weights(
    const float* __restrict__ wa, const float* __restrict__ wb,
    const float* __restrict__ wc, const float* __restrict__ wd,
    u16* __restrict__ dst)
{
    int m = blockIdx.y;
    const float* src = (m==0)? wa : (m==1)? wb : (m==2)? wc : wd;
    u16* d = dst + (size_t)m * (1024u*1024u);
    int tid = blockIdx.x * blockDim.x + threadIdx.x;   // 0..131071
    int sub = tid & 3;
    int row = (tid >> 2) & 1023;
    int kb  = tid >> 12;                               // 0..31
    const float4* s4 = (const float4*)(src + row*1024 + kb*32 + sub*8);
    float4 a = s4[0], b = s4[1];
    Pack8 p;
    p.s[0]=f2bf(a.x); p.s[1]=f2bf(a.y); p.s[2]=f2bf(a.z); p.s[3]=f2bf(a.w);
    p.s[4]=f2bf(b.x); p.s[5]=f2bf(b.y); p.s[6]=f2bf(b.z); p.s[7]=f2bf(b.w);
    ((uint4*)d)[(kb*1024 + row)*4 + sub] = p.u4;
}

// One wave computes 4 col-tiles (cols C0..C0+63) for all 64 nodes, in ONE
// pass. 16 MFMA per {4 B-loads (L2, JIT batch) + 4 A ds_read_b128}. Register
// shape: acc = 64 AGPR + ~50 working VGPR — exactly the 128/wave budget at
// 16 waves/CU. r5 lesson: the 32x32 f32x16 variant spills (~1GB scratch);
// this 16x16 f32x4 shape is the proven no-spill point. Do not touch.
__device__ __forceinline__ void gemm_quad1(
    const u16* __restrict__ Wp, const u16* xs,
    int C0, int lane15, int q, f32x4 acc[4][4])
{
    const uint4* bb = (const uint4*)Wp + (C0 + lane15)*4 + q;
    const uint4* ab = (const uint4*)xs + q*64 + lane15;
    #pragma unroll
    for (int t=0; t<4; ++t)
      #pragma unroll
      for (int rt=0; rt<4; ++rt)
        acc[t][rt] = (f32x4){0.f,0.f,0.f,0.f};
    #pragma unroll 2
    for (int ks=0; ks<32; ++ks){
        Pack8 b[4], a[4];
        #pragma unroll
        for (int t=0; t<4; ++t) b[t].u4 = bb[ks*4096 + t*64];
        #pragma unroll
        for (int rt=0; rt<4; ++rt) a[rt].u4 = ab[ks*256 + rt*16];
        #pragma unroll
        for (int t=0; t<4; ++t)
          #pragma unroll
          for (int rt=0; rt<4; ++rt)
            acc[t][rt] = __builtin_amdgcn_mfma_f32_16x16x32_bf16(a[rt].bf, b[t].bf, acc[t][rt], 0,0,0);
    }
}

// LDS layout (floats):
//   [0, 32832)       : xs (bf16 activations, 131072 B) / later sbuf (fp32 h2)
//   [32832, +64*VSTR): vbuf, per-node padded v rows
//   then 128 floats  : stats (64 nodes x {sum, sumsq})
template<int MDIM>
__device__ __forceinline__ void gal_body(
    const int blk, char* smem,
    const float* __restrict__ f,
    const float* __restrict__ ln1g, const float* __restrict__ ln1b,
    const float* __restrict__ ln2g, const float* __restrict__ ln2b,
    const float* __restrict__ b2,
    const u16* __restrict__ Wp1, const u16* __restrict__ Wp2,
    float* __restrict__ outp)
{
    constexpr int VSTR = 32*MDIM + 4;           // padded node stride (floats)
    constexpr int SBS  = 64*32 + 4;             // sbuf per-slot stride = 2052
    u16*   xs    = (u16*)smem;
    float* sbuf  = (float*)smem;
    float* vbuf  = (float*)smem + 32832;
    float* stats = (float*)smem + 32832 + 64*VSTR;

    const int tid    = threadIdx.x;            // 0..1023
    const int lane   = tid & 63;
    const int wv     = tid >> 6;               // wave 0..15
    const int lane15 = lane & 15;
    const int q      = lane >> 4;
    const int node0  = blk * 64;

    // ---- Phase 0: zero stats, stage v tile (float4, padded, zero-fill)
    if (tid < 128) stats[tid] = 0.f;
    {
        float4* vbuf4 = (float4*)vbuf;
        const int gv4  = node0*8*MDIM;          // block base in float4 units
        const int lim4 = NN*8*MDIM;
        for (int i = tid; i < 64*8*MDIM; i += 1024){
            int nd = i / (8*MDIM);
            int r4 = i - nd*(8*MDIM);
            float4 val = (gv4 + i < lim4) ? ((const float4*)f)[gv4 + i]
                                          : (float4){0.f,0.f,0.f,0.f};
            vbuf4[nd*(VSTR/4) + r4] = val;
        }
    }
    __syncthreads();

    // ---- Phase 1: gram + LN1 + lrelu -> xs (bf16, [k>>3][node][k&7])
    // NEW partition (r3 form was 288 broadcast ds_read_b32/thread = P1 is
    // LDS-issue bound; r1/r4 register fixes at 16 threads/node spilled):
    // TWO half-node passes, 32 threads/node; thread owns ONE gram row a
    // (k = a*32..a*32+31) -> d[32] fits registers (acc not live in P1),
    // dots computed ONCE, packed straight from regs. vn streamed as float2;
    // ln1g/ln1b are per-thread contiguous -> float4 loads. Stats reduce via
    // shfl_xor strides 1..16 within each 32-lane half (node bdry at lane 32).
    #pragma unroll
    for (int pass=0; pass<2; ++pass){
        const int n = pass*32 + (tid>>5);
        const int a = tid & 31;
        const float* vn = vbuf + n*VSTR;
        float va[MDIM];
        #pragma unroll
        for (int c=0;c<MDIM;++c) va[c] = vn[a*MDIM+c];
        float d[32];
        {
            const float2* vn2 = (const float2*)vn;
            float cur = 0.f;
            constexpr int NF2 = (32*MDIM)/2;        // 16 or 48
            #pragma unroll
            for (int f2=0; f2<NF2; ++f2){
                float2 q2 = vn2[f2];
                #pragma unroll
                for (int e=0;e<2;++e){
                    const int fi = 2*f2 + e;
                    const int b  = fi / MDIM;        // compile-time
                    const int c  = fi % MDIM;        // compile-time
                    cur += va[c] * ((e==0)? q2.x : q2.y);
                    if (c == MDIM-1){ d[b] = cur; cur = 0.f; }
                }
            }
        }
        float sum=0.f, ssum=0.f;
        #pragma unroll
        for (int b=0;b<32;++b){ sum += d[b]; ssum += d[b]*d[b]; }
        #pragma unroll
        for (int st=1; st<32; st<<=1){ sum += __shfl_xor(sum, st); ssum += __shfl_xor(ssum, st); }
        float mu   = sum * (1.f/1024.f);
        float rstd = rsqrtf(ssum*(1.f/1024.f) - mu*mu + LN_EPS);
        #pragma unroll
        for (int jb=0;jb<4;++jb){
            float4 g0 = *(const float4*)(ln1g + a*32 + jb*8);
            float4 g1 = *(const float4*)(ln1g + a*32 + jb*8 + 4);
            float4 h0 = *(const float4*)(ln1b + a*32 + jb*8);
            float4 h1 = *(const float4*)(ln1b + a*32 + jb*8 + 4);
            Pack8 p;
            #pragma unroll
            for (int l=0;l<8;++l){
                const float g = (l==0)?g0.x:(l==1)?g0.y:(l==2)?g0.z:(l==3)?g0.w
                               :(l==4)?g1.x:(l==5)?g1.y:(l==6)?g1.z:g1.w;
                const float hb= (l==0)?h0.x:(l==1)?h0.y:(l==2)?h0.z:(l==3)?h0.w
                               :(l==4)?h1.x:(l==5)?h1.y:(l==6)?h1.z:h1.w;
                float x = (d[jb*8+l] - mu)*rstd*g + hb;
                x = (x >= 0.f)? x : SLOPE*x;
                p.s[l] = f2bf(x);
            }
            ((uint4*)xs)[(a*4 + jb)*64 + n] = p.u4;   // kb = a*4+jb (layout unchanged)
        }
    }
    __syncthreads();

    // ---- Phase 2: h1 = x1 @ W1^T, one pass, wave wv owns cols wv*64..+63.
    // Stats via fold-tree + one atomic pair; acc stays live in AGPRs.
    {
        f32x4 acc[4][4];
        gemm_quad1(Wp1, xs, wv*64, lane15, q, acc);
        {
            float p_[16], pp_[16];
            #pragma unroll
            for (int idx=0; idx<16; ++idx){
                int rt = idx>>2, rr = idx&3;
                float s=0.f, s2=0.f;
                #pragma unroll
                for (int t=0; t<4; ++t){ float h = acc[t][rt][rr]; s += h; s2 += h*h; }
                p_[idx] = s; pp_[idx] = s2;
            }
            // fold over lane15: lane15==l ends with totals for idx l in [0]
            #pragma unroll
            for (int m=8; m>=1; m>>=1){
                const bool hi = (lane15 & m) != 0;
                #pragma unroll
                for (int i=0; i<m; ++i){
                    float sp = hi ? p_[i]  : p_[i+m];
                    float kp = hi ? p_[i+m]  : p_[i];
                    p_[i]  = kp + __shfl_xor(sp, m);
                    float sq = hi ? pp_[i] : pp_[i+m];
                    float kq = hi ? pp_[i+m] : pp_[i];
                    pp_[i] = kq + __shfl_xor(sq, m);
                }
            }
            int nd = (lane15>>2)*16 + q*4 + (lane15&3);
            atomicAdd(&stats[2*nd],   p_[0]);
            atomicAdd(&stats[2*nd+1], pp_[0]);
        }
        __syncthreads();   // stats final AND all GEMM1 xs reads drained

        // ---- Phase 3: LN2 + lrelu applied to acc in regs -> x2 into xs
        float g2c[4], b2c[4];
        #pragma unroll
        for (int t=0; t<4; ++t){
            int col = wv*64 + t*16 + lane15;
            g2c[t] = ln2g[col];
            b2c[t] = ln2b[col];
        }
        #pragma unroll
        for (int rt=0; rt<4; ++rt)
          #pragma unroll
          for (int rr=0; rr<4; ++rr){
            int nd = rt*16 + q*4 + rr;
            float mu   = stats[2*nd]*(1.f/1024.f);
            float rstd = rsqrtf(stats[2*nd+1]*(1.f/1024.f) - mu*mu + LN_EPS);
            #pragma unroll
            for (int t=0; t<4; ++t){
                float h = acc[t][rt][rr];
                float x = (h - mu)*rstd*g2c[t] + b2c[t];
                x = (x >= 0.f)? x : SLOPE*x;
                int col = wv*64 + t*16 + lane15;
                xs[(col>>3)*512 + nd*8 + (col&7)] = f2bf(x);
            }
          }
    }
    __syncthreads();

    // ---- Phase 4: h2 = x2 @ W2^T + b2, one pass (acc[4][4] live). Two
    // staging rounds (round ps stages a-group wv*2+ps); consume threads keep
    // BOTH rounds' results in registers, park them in a contiguous LDS image
    // once the strips are dead, then one block-wide float4 pass writes full
    // 128B lines exactly once.
    {
        f32x4 acc[4][4];
        gemm_quad1(Wp2, xs, wv*64, lane15, q, acc);
        float bias[4];
        #pragma unroll
        for (int t=0; t<4; ++t)
            bias[t] = b2[wv*64 + t*16 + lane15];
        __syncthreads();   // all xs reads complete before sbuf overwrite

        const int nd_c = tid >> 4;      // consume node
        const int s_c  = tid & 15;      // consume strip -> a = 2*s_c + ps
        float keep[2][MDIM];

        #pragma unroll
        for (int ps=0; ps<2; ++ps){
            // stage strip a = wv*2 + ps : sbuf[wv][node][b]
            #pragma unroll
            for (int ctl=0; ctl<2; ++ctl){
                const int t = ps*2 + ctl;
                #pragma unroll
                for (int rt=0; rt<4; ++rt)
                  #pragma unroll
                  for (int rr=0; rr<4; ++rr){
                    int nd = rt*16 + q*4 + rr;
                    sbuf[wv*SBS + nd*32 + ctl*16 + lane15] = acc[t][rt][rr] + bias[t];
                  }
            }
            __syncthreads();
            // consume: softmax + attn @ v, result -> keep[ps] (registers)
            {
                const float* hp = sbuf + s_c*SBS + nd_c*32;
                float e[32];
                #pragma unroll
                for (int r=0;r<8;++r){
                    float4 v4 = ((const float4*)hp)[r];
                    e[4*r]=v4.x; e[4*r+1]=v4.y; e[4*r+2]=v4.z; e[4*r+3]=v4.w;
                }
                float mx = e[0];
                #pragma unroll
                for (int b=1;b<32;++b) mx = fmaxf(mx, e[b]);
                float sm = 0.f;
                #pragma unroll
                for (int b=0;b<32;++b){ e[b] = __expf(e[b]-mx); sm += e[b]; }
                float inv = 1.f / sm;
                float oacc[MDIM];
                #pragma unroll
                for (int c=0;c<MDIM;++c) oacc[c]=0.f;
                const float4* vr = (const float4*)(vbuf + nd_c*VSTR);
                #pragma unroll
                for (int r=0; r<8*MDIM; ++r){
                    float4 v4 = vr[r];
                    #pragma unroll
                    for (int t=0;t<4;++t){
                        const int fi = 4*r+t;
                        const int b  = fi/MDIM;
                        const int c  = fi - b*MDIM;
                        float comp = (t==0)?v4.x:(t==1)?v4.y:(t==2)?v4.z:v4.w;
                        oacc[c] += e[b]*comp;
                    }
                }
                #pragma unroll
                for (int c=0;c<MDIM;++c) keep[ps][c] = oacc[c]*inv;
            }
            __syncthreads();   // strip reads done (ps0: before restage; ps1: before img)
        }

        // park both rounds into contiguous image at smem base (strips + vbuf dead)
        {
            float* img = sbuf;
            #pragma unroll
            for (int c=0;c<MDIM;++c){
                img[nd_c*(32*MDIM) + (2*s_c  )*MDIM + c] = keep[0][c];
                img[nd_c*(32*MDIM) + (2*s_c+1)*MDIM + c] = keep[1][c];
            }
        }
        __syncthreads();

        // coalesced full-line writeback, float4, each line written once
        {
            const float4* img4 = (const float4*)sbuf;
            float4* out4 = (float4*)(outp + (size_t)node0*(32*MDIM));
            constexpr int NPV = 8*MDIM;          // float4 per node
            for (int i = tid; i < 64*NPV; i += 1024){
                int nd = (MDIM==1) ? (i >> 3) : (i / NPV);
                if (node0 + nd < NN) out4[i] = img4[i];
            }
        }
    }
}

// Single launch, CONTIGUOUS type halves. Blocks dispatch ~in gid order with
// a ~256-block resident window (1 block/CU), so contiguous halves keep one
// 4MB weight set per XCD except during the brief boundary crossing, while
// the scheduler back-fills the first half's drain with second-half blocks.
// Long type (MDIM3) first, short last -> minimal final drain.
__global__ __launch_bounds__(1024, 4) void gal_fused_all(
    const float* __restrict__ f0, const float* __restrict__ f1,
    const float* __restrict__ ln1g0, const float* __restrict__ ln1b0,
    const float* __restrict__ ln2g0, const float* __restrict__ ln2b0,
    const float* __restrict__ b2_0,
    const float* __restrict__ ln1g1, const float* __restrict__ ln1b1,
    const float* __restrict__ ln2g1, const float* __restrict__ ln2b1,
    const float* __restrict__ b2_1,
    const u16* __restrict__ wp, float* __restrict__ out)
{
    extern __shared__ char smem[];
    const int gid = blockIdx.x;
    if (gid < NB)
        gal_body<3>(gid, smem, f1, ln1g1, ln1b1, ln2g1, ln2b1, b2_1,
                    wp + 2097152,  wp + 3145728, out + (size_t)NN*32);
    else
        gal_body<1>(gid - NB, smem, f0, ln1g0, ln1b0, ln2g0, ln2b0, b2_0,
                    wp,            wp + 1048576, out);
}

extern "C" void kernel_launch(void* const* d_in, const int* in_sizes, int n_in,
                              void* d_out, int out_size, void* d_ws, size_t ws_size,
                              hipStream_t stream)
{
    const float* f0    = (const float*)d_in[0];
    const float* f1    = (const float*)d_in[1];
    const float* ln1g0 = (const float*)d_in[2];
    const float* ln1b0 = (const float*)d_in[3];
    const float* w1_0  = (const float*)d_in[4];
    const float* ln2g0 = (const float*)d_in[5];
    const float* ln2b0 = (const float*)d_in[6];
    const float* w2_0  = (const float*)d_in[7];
    const float* b2_0  = (const float*)d_in[8];
    const float* ln1g1 = (const float*)d_in[9];
    const float* ln1b1 = (const float*)d_in[10];
    const float* w1_1  = (const float*)d_in[11];
    const float* ln2g1 = (const float*)d_in[12];
    const float* ln2b1 = (const float*)d_in[13];
    const float* w2_1  = (const float*)d_in[14];
    const float* b2_1  = (const float*)d_in[15];
    float* out = (float*)d_out;
    u16* wp = (u16*)d_ws;    // 4 packed matrices x 2 MB = 8 MB scratch

    const int smem = (32832 + 64*(32*3+4) + 128)*4;   // 157440 (max of both)
    (void)hipFuncSetAttribute(reinterpret_cast<const void*>(&gal_fused_all),
                              hipFuncAttributeMaxDynamicSharedMemorySize, smem);

    prep_weights<<<dim3(128,4), 1024, 0, stream>>>(w1_0, w2_0, w1_1, w2_1, wp);
    gal_fused_all<<<2*NB, 1024, smem, stream>>>(f0, f1,
        ln1g0, ln1b0, ln2g0, ln2b0, b2_0,
        ln1g1, ln1b1, ln2g1, ln2b1, b2_1,
        wp, out);
}